// Round 1
// baseline (317.662 us; speedup 1.0000x reference)
//
#include <hip/hip_runtime.h>
#include <hip/hip_bf16.h>

#define NN 10000
#define NE 160000
#define NET 170000   // edges + self loops
#define IN_DIM 512
#define D1 1024      // HEADS*HID
#define HEADS 4
#define HID 256
#define OUT_DIM 512
#define NEG_SLOPE 0.2f

typedef __attribute__((ext_vector_type(8))) short bf16x8;
typedef __attribute__((ext_vector_type(4))) float f32x4;

__device__ inline float b2f(unsigned short b) {
    union { unsigned u; float f; } x; x.u = ((unsigned)b) << 16; return x.f;
}
__device__ inline unsigned short f2b(float f) {
    union { float f; unsigned u; } x; x.f = f;
    unsigned u = x.u;
    unsigned r = u + 0x7FFFu + ((u >> 16) & 1u);
    return (unsigned short)(r >> 16);
}
__device__ inline float lrelu(float v) { return v > 0.f ? v : NEG_SLOPE * v; }

// ---- edge_index dtype detection: int64 -> every high word of first values is 0
__global__ void detect_kernel(const int* ei32, int* flag) {
    __shared__ int nz;
    if (threadIdx.x == 0) nz = 0;
    __syncthreads();
    int acc = 0;
    for (int i = threadIdx.x; i < 500; i += 256) acc |= ei32[2 * i + 1];
    if (acc) atomicOr(&nz, 1);
    __syncthreads();
    if (threadIdx.x == 0) flag[0] = (nz == 0) ? 1 : 0;
}

__device__ inline void load_edge(const void* ei, int f64, int e, int& s, int& d) {
    if (f64) {
        const long long* p = (const long long*)ei;
        s = (int)p[e]; d = (int)p[NE + e];
    } else {
        const int* p = (const int*)ei;
        s = p[e]; d = p[NE + e];
    }
}

__global__ void zero2_kernel(int* a, int* b, int n) {
    int i = blockIdx.x * blockDim.x + threadIdx.x;
    if (i < n) { a[i] = 0; b[i] = 0; }
}

__global__ void count_kernel(const void* ei, const int* flag, int* counts) {
    int e = blockIdx.x * blockDim.x + threadIdx.x;
    if (e >= NET) return;
    int s, d;
    if (e < NE) load_edge(ei, *flag, e, s, d);
    else d = e - NE;
    atomicAdd(&counts[d], 1);
}

__global__ __launch_bounds__(256) void scan_kernel(const int* counts, int* indptr) {
    __shared__ int part[256];
    int t = threadIdx.x;
    int base = t * 40;
    int local[40];
    int sum = 0;
#pragma unroll
    for (int k = 0; k < 40; k++) {
        int i = base + k;
        int c = (i < NN) ? counts[i] : 0;
        local[k] = sum;
        sum += c;
    }
    part[t] = sum;
    __syncthreads();
    for (int off = 1; off < 256; off <<= 1) {
        int v = (t >= off) ? part[t - off] : 0;
        __syncthreads();
        part[t] += v;
        __syncthreads();
    }
    int excl = part[t] - sum;
#pragma unroll
    for (int k = 0; k < 40; k++) {
        int i = base + k;
        if (i < NN) indptr[i] = excl + local[k];
    }
    if (t == 255) indptr[NN] = part[255];
}

__global__ void fill_kernel(const void* ei, const int* flag, const int* indptr,
                            int* cursor, int* csr_src) {
    int e = blockIdx.x * blockDim.x + threadIdx.x;
    if (e >= NET) return;
    int s, d;
    if (e < NE) load_edge(ei, *flag, e, s, d);
    else { s = e - NE; d = s; }
    int pos = indptr[d] + atomicAdd(&cursor[d], 1);
    csr_src[pos] = s;
}

// ---- f32 -> bf16 convert, 4 elems/thread
__global__ void cvt_kernel(const float* __restrict__ in, unsigned short* __restrict__ out, int n4) {
    int i = blockIdx.x * blockDim.x + threadIdx.x;
    if (i >= n4) return;
    float4 v = reinterpret_cast<const float4*>(in)[i];
    ushort4 o;
    o.x = f2b(v.x); o.y = f2b(v.y); o.z = f2b(v.z); o.w = f2b(v.w);
    reinterpret_cast<ushort4*>(out)[i] = o;
}

// ---- W [R][C] f32 -> Wt [C][R] bf16 (tiled transpose)
__global__ __launch_bounds__(256) void tpose_kernel(const float* __restrict__ in,
                                                    unsigned short* __restrict__ out,
                                                    int R, int C) {
    __shared__ float tile[32][33];
    int tx = threadIdx.x & 31, ty = threadIdx.x >> 5;
    int c = blockIdx.x * 32 + tx;
#pragma unroll
    for (int r0 = 0; r0 < 32; r0 += 8) {
        int r = blockIdx.y * 32 + ty + r0;
        tile[ty + r0][tx] = (r < R && c < C) ? in[(size_t)r * C + c] : 0.f;
    }
    __syncthreads();
    int oc = blockIdx.y * 32 + tx;   // R-dim
#pragma unroll
    for (int r0 = 0; r0 < 32; r0 += 8) {
        int orow = blockIdx.x * 32 + ty + r0;  // C-dim
        if (orow < C && oc < R)
            out[(size_t)orow * R + oc] = f2b(tile[tx][ty + r0]);
    }
}

// ---- C[M][N] = A[M][K](bf16) @ B[N][K](bf16)^T ; optional bias; write f32 and/or bf16
#define BM 64
#define BN 64
#define BK 32
__global__ __launch_bounds__(256) void gemm_bt(
    const unsigned short* __restrict__ A, const unsigned short* __restrict__ B,
    const float* __restrict__ bias, float* __restrict__ Cf, unsigned short* __restrict__ Cb,
    int M, int N, int K) {
    __shared__ __align__(16) unsigned short As[BM][BK];
    __shared__ __align__(16) unsigned short Bs[BN][BK];
    int t = threadIdx.x;
    int row0 = blockIdx.x * BM, col0 = blockIdx.y * BN;
    int w = t >> 6, l = t & 63;
    int wr = w >> 1, wc = w & 1;
    f32x4 acc[2][2] = {};
    int sr = t >> 2;
    int sc = (t & 3) * 8;
    for (int k0 = 0; k0 < K; k0 += BK) {
        int gr = row0 + sr;
        if (gr < M) {
            uint4 v = *reinterpret_cast<const uint4*>(A + (size_t)gr * K + k0 + sc);
            *reinterpret_cast<uint4*>(&As[sr][sc]) = v;
        } else {
            uint4 z = {0, 0, 0, 0};
            *reinterpret_cast<uint4*>(&As[sr][sc]) = z;
        }
        uint4 v2 = *reinterpret_cast<const uint4*>(B + (size_t)(col0 + sr) * K + k0 + sc);
        *reinterpret_cast<uint4*>(&Bs[sr][sc]) = v2;
        __syncthreads();
        int kk = (l >> 4) * 8;
        int rr = l & 15;
        bf16x8 af[2], bfv[2];
#pragma unroll
        for (int mi = 0; mi < 2; mi++)
            af[mi] = *reinterpret_cast<const bf16x8*>(&As[wr * 32 + mi * 16 + rr][kk]);
#pragma unroll
        for (int ni = 0; ni < 2; ni++)
            bfv[ni] = *reinterpret_cast<const bf16x8*>(&Bs[wc * 32 + ni * 16 + rr][kk]);
#pragma unroll
        for (int mi = 0; mi < 2; mi++)
#pragma unroll
            for (int ni = 0; ni < 2; ni++)
                acc[mi][ni] = __builtin_amdgcn_mfma_f32_16x16x32_bf16(af[mi], bfv[ni], acc[mi][ni], 0, 0, 0);
        __syncthreads();
    }
    // C/D: col = lane&15, row = (lane>>4)*4 + j
    int c_l = l & 15, r_h = (l >> 4) * 4;
#pragma unroll
    for (int mi = 0; mi < 2; mi++)
#pragma unroll
        for (int ni = 0; ni < 2; ni++) {
            int gc = col0 + wc * 32 + ni * 16 + c_l;
#pragma unroll
            for (int j = 0; j < 4; j++) {
                int gr = row0 + wr * 32 + mi * 16 + r_h + j;
                if (gr < M) {
                    float v = acc[mi][ni][j];
                    if (bias) v += bias[gc];
                    if (Cf) Cf[(size_t)gr * N + gc] = v;
                    if (Cb) Cb[(size_t)gr * N + gc] = f2b(v);
                }
            }
        }
}

// ---- a_src/a_dst: per node, per head dot(h[n,h,:], att[h,:]); wave == head
__global__ __launch_bounds__(256) void att_kernel(const unsigned short* __restrict__ hb,
                                                  const float* __restrict__ att_s,
                                                  const float* __restrict__ att_d,
                                                  float* __restrict__ aS, float* __restrict__ aD) {
    int n = blockIdx.x;
    int t = threadIdx.x;
    int head = t >> 6, lane = t & 63;
    const unsigned short* hrow = hb + (size_t)n * D1 + head * HID + lane * 4;
    ushort4 hv = *reinterpret_cast<const ushort4*>(hrow);
    float4 as = *reinterpret_cast<const float4*>(att_s + head * HID + lane * 4);
    float4 ad = *reinterpret_cast<const float4*>(att_d + head * HID + lane * 4);
    float h0 = b2f(hv.x), h1 = b2f(hv.y), h2 = b2f(hv.z), h3 = b2f(hv.w);
    float ps = h0 * as.x + h1 * as.y + h2 * as.z + h3 * as.w;
    float pd = h0 * ad.x + h1 * ad.y + h2 * ad.z + h3 * ad.w;
#pragma unroll
    for (int off = 32; off; off >>= 1) {
        ps += __shfl_xor(ps, off);
        pd += __shfl_xor(pd, off);
    }
    if (lane == 0) {
        aS[n * HEADS + head] = ps;
        aD[n * HEADS + head] = pd;
    }
}

// ---- per-dst-node softmax + aggregation, fused bias+ReLU, bf16 out
__global__ __launch_bounds__(256) void agg_kernel(const unsigned short* __restrict__ hb,
                                                  const float* __restrict__ aS,
                                                  const float* __restrict__ aD,
                                                  const int* __restrict__ indptr,
                                                  const int* __restrict__ csr_src,
                                                  const float* __restrict__ bias,
                                                  unsigned short* __restrict__ outb) {
    int i = blockIdx.x;
    int t = threadIdx.x;
    int beg = indptr[i], end = indptr[i + 1];
    int deg = end - beg;
    __shared__ float sm[HEADS], ss[HEADS];
    __shared__ float alpha_s[64 * HEADS];
    __shared__ int src_s[64];
    float4 adst = *reinterpret_cast<const float4*>(aD + i * HEADS);
    // phase 1 (wave 0): per-head max then sum of exp
    if (t < 64) {
        float mx[4] = {-1e30f, -1e30f, -1e30f, -1e30f};
        for (int j = t; j < deg; j += 64) {
            int s = csr_src[beg + j];
            float4 asrc = *reinterpret_cast<const float4*>(aS + s * HEADS);
            mx[0] = fmaxf(mx[0], lrelu(asrc.x + adst.x));
            mx[1] = fmaxf(mx[1], lrelu(asrc.y + adst.y));
            mx[2] = fmaxf(mx[2], lrelu(asrc.z + adst.z));
            mx[3] = fmaxf(mx[3], lrelu(asrc.w + adst.w));
        }
#pragma unroll
        for (int off = 32; off; off >>= 1) {
#pragma unroll
            for (int h = 0; h < 4; h++) mx[h] = fmaxf(mx[h], __shfl_xor(mx[h], off));
        }
        float sum[4] = {0.f, 0.f, 0.f, 0.f};
        for (int j = t; j < deg; j += 64) {
            int s = csr_src[beg + j];
            float4 asrc = *reinterpret_cast<const float4*>(aS + s * HEADS);
            sum[0] += __expf(lrelu(asrc.x + adst.x) - mx[0]);
            sum[1] += __expf(lrelu(asrc.y + adst.y) - mx[1]);
            sum[2] += __expf(lrelu(asrc.z + adst.z) - mx[2]);
            sum[3] += __expf(lrelu(asrc.w + adst.w) - mx[3]);
        }
#pragma unroll
        for (int off = 32; off; off >>= 1) {
#pragma unroll
            for (int h = 0; h < 4; h++) sum[h] += __shfl_xor(sum[h], off);
        }
        if (t == 0) {
#pragma unroll
            for (int h = 0; h < 4; h++) { sm[h] = mx[h]; ss[h] = sum[h] + 1e-16f; }
        }
    }
    __syncthreads();
    // phase 2: chunked aggregation; thread t owns channels 4t..4t+3 (head t>>6)
    int head = t >> 6;
    float acc0 = 0.f, acc1 = 0.f, acc2 = 0.f, acc3 = 0.f;
    for (int c0 = 0; c0 < deg; c0 += 64) {
        int nj = min(64, deg - c0);
        if (t < nj) {
            int s = csr_src[beg + c0 + t];
            src_s[t] = s;
            float4 asrc = *reinterpret_cast<const float4*>(aS + s * HEADS);
            alpha_s[t * 4 + 0] = __expf(lrelu(asrc.x + adst.x) - sm[0]) / ss[0];
            alpha_s[t * 4 + 1] = __expf(lrelu(asrc.y + adst.y) - sm[1]) / ss[1];
            alpha_s[t * 4 + 2] = __expf(lrelu(asrc.z + adst.z) - sm[2]) / ss[2];
            alpha_s[t * 4 + 3] = __expf(lrelu(asrc.w + adst.w) - sm[3]) / ss[3];
        }
        __syncthreads();
        for (int j = 0; j < nj; j++) {
            int s = src_s[j];
            float wgt = alpha_s[j * 4 + head];
            ushort4 hv = *reinterpret_cast<const ushort4*>(hb + (size_t)s * D1 + t * 4);
            acc0 += wgt * b2f(hv.x);
            acc1 += wgt * b2f(hv.y);
            acc2 += wgt * b2f(hv.z);
            acc3 += wgt * b2f(hv.w);
        }
        __syncthreads();
    }
    float4 bv = *reinterpret_cast<const float4*>(bias + t * 4);
    ushort4 o;
    o.x = f2b(fmaxf(acc0 + bv.x, 0.f));
    o.y = f2b(fmaxf(acc1 + bv.y, 0.f));
    o.z = f2b(fmaxf(acc2 + bv.z, 0.f));
    o.w = f2b(fmaxf(acc3 + bv.w, 0.f));
    *reinterpret_cast<ushort4*>(outb + (size_t)i * D1 + t * 4) = o;
}

extern "C" void kernel_launch(void* const* d_in, const int* in_sizes, int n_in,
                              void* d_out, int out_size, void* d_ws, size_t ws_size,
                              hipStream_t stream) {
    const float* x   = (const float*)d_in[0];
    const void*  ei  = d_in[1];
    const float* W1  = (const float*)d_in[2];
    const float* as1 = (const float*)d_in[3];
    const float* ad1 = (const float*)d_in[4];
    const float* b1  = (const float*)d_in[5];
    const float* W2  = (const float*)d_in[6];
    const float* as2 = (const float*)d_in[7];
    const float* ad2 = (const float*)d_in[8];
    const float* b2  = (const float*)d_in[9];
    const float* fcW = (const float*)d_in[10];
    const float* fcb = (const float*)d_in[11];
    float* out = (float*)d_out;

    char* ws = (char*)d_ws;
    size_t o = 0;
    auto carve = [&](size_t bytes) -> char* {
        char* p = ws + o;
        o = (o + bytes + 255) & ~(size_t)255;
        return p;
    };
    unsigned short* xb   = (unsigned short*)carve((size_t)NN * IN_DIM * 2);
    unsigned short* hb   = (unsigned short*)carve((size_t)NN * D1 * 2);
    unsigned short* x2b  = (unsigned short*)carve((size_t)NN * D1 * 2);
    unsigned short* W1t  = (unsigned short*)carve((size_t)D1 * IN_DIM * 2);
    unsigned short* W2t  = (unsigned short*)carve((size_t)D1 * D1 * 2);
    unsigned short* fcWt = (unsigned short*)carve((size_t)OUT_DIM * D1 * 2);
    float* aS   = (float*)carve((size_t)NN * HEADS * 4);
    float* aD   = (float*)carve((size_t)NN * HEADS * 4);
    int* counts = (int*)carve((size_t)NN * 4);
    int* cursor = (int*)carve((size_t)NN * 4);
    int* indptr = (int*)carve((size_t)(NN + 1) * 4);
    int* csr_src= (int*)carve((size_t)NET * 4);
    int* flag   = (int*)carve(4);
    (void)ws_size; (void)in_sizes; (void)n_in; (void)out_size;

    // CSR build (dtype-agnostic edge loads)
    detect_kernel<<<1, 256, 0, stream>>>((const int*)ei, flag);
    zero2_kernel<<<(NN + 255) / 256, 256, 0, stream>>>(counts, cursor, NN);
    count_kernel<<<(NET + 255) / 256, 256, 0, stream>>>(ei, flag, counts);
    scan_kernel<<<1, 256, 0, stream>>>(counts, indptr);
    fill_kernel<<<(NET + 255) / 256, 256, 0, stream>>>(ei, flag, indptr, cursor, csr_src);

    // bf16 conversions
    cvt_kernel<<<(NN * IN_DIM / 4 + 255) / 256, 256, 0, stream>>>(x, xb, NN * IN_DIM / 4);
    tpose_kernel<<<dim3(D1 / 32, IN_DIM / 32), 256, 0, stream>>>(W1, W1t, IN_DIM, D1);
    tpose_kernel<<<dim3(D1 / 32, D1 / 32), 256, 0, stream>>>(W2, W2t, D1, D1);
    tpose_kernel<<<dim3(OUT_DIM / 32, D1 / 32), 256, 0, stream>>>(fcW, fcWt, D1, OUT_DIM);

    const int MB = (NN + BM - 1) / BM;  // 157
    // layer 1
    gemm_bt<<<dim3(MB, D1 / BN), 256, 0, stream>>>(xb, W1t, nullptr, nullptr, hb, NN, D1, IN_DIM);
    att_kernel<<<NN, 256, 0, stream>>>(hb, as1, ad1, aS, aD);
    agg_kernel<<<NN, 256, 0, stream>>>(hb, aS, aD, indptr, csr_src, b1, x2b);
    // layer 2
    gemm_bt<<<dim3(MB, D1 / BN), 256, 0, stream>>>(x2b, W2t, nullptr, nullptr, hb, NN, D1, D1);
    att_kernel<<<NN, 256, 0, stream>>>(hb, as2, ad2, aS, aD);
    agg_kernel<<<NN, 256, 0, stream>>>(hb, aS, aD, indptr, csr_src, b2, x2b);
    // final fc (bias, f32 out)
    gemm_bt<<<dim3(MB, OUT_DIM / BN), 256, 0, stream>>>(x2b, fcWt, fcb, out, nullptr, NN, OUT_DIM, D1);
}

// Round 2
// 285.917 us; speedup vs baseline: 1.1110x; 1.1110x over previous
//
#include <hip/hip_runtime.h>
#include <hip/hip_bf16.h>

#define NN 10000
#define NE 160000
#define NET 170000   // edges + self loops
#define IN_DIM 512
#define D1 1024      // HEADS*HID
#define HEADS 4
#define HID 256
#define OUT_DIM 512
#define NEG_SLOPE 0.2f

typedef __attribute__((ext_vector_type(8))) short bf16x8;
typedef __attribute__((ext_vector_type(4))) float f32x4;

__device__ inline float b2f(unsigned short b) {
    union { unsigned u; float f; } x; x.u = ((unsigned)b) << 16; return x.f;
}
__device__ inline unsigned short f2b(float f) {
    union { float f; unsigned u; } x; x.f = f;
    unsigned u = x.u;
    unsigned r = u + 0x7FFFu + ((u >> 16) & 1u);
    return (unsigned short)(r >> 16);
}
__device__ inline float lrelu(float v) { return v > 0.f ? v : NEG_SLOPE * v; }

// ---- edge_index dtype detection: int64 -> every high word of first values is 0
__global__ void detect_kernel(const int* ei32, int* flag) {
    __shared__ int nz;
    if (threadIdx.x == 0) nz = 0;
    __syncthreads();
    int acc = 0;
    for (int i = threadIdx.x; i < 500; i += 256) acc |= ei32[2 * i + 1];
    if (acc) atomicOr(&nz, 1);
    __syncthreads();
    if (threadIdx.x == 0) flag[0] = (nz == 0) ? 1 : 0;
}

__device__ inline void load_edge(const void* ei, int f64, int e, int& s, int& d) {
    if (f64) {
        const long long* p = (const long long*)ei;
        s = (int)p[e]; d = (int)p[NE + e];
    } else {
        const int* p = (const int*)ei;
        s = p[e]; d = p[NE + e];
    }
}

__global__ void zero2_kernel(int* a, int* b, int n) {
    int i = blockIdx.x * blockDim.x + threadIdx.x;
    if (i < n) { a[i] = 0; b[i] = 0; }
}

__global__ void count_kernel(const void* ei, const int* flag, int* counts) {
    int e = blockIdx.x * blockDim.x + threadIdx.x;
    if (e >= NET) return;
    int s, d;
    if (e < NE) load_edge(ei, *flag, e, s, d);
    else d = e - NE;
    atomicAdd(&counts[d], 1);
}

__global__ __launch_bounds__(256) void scan_kernel(const int* counts, int* indptr) {
    __shared__ int part[256];
    int t = threadIdx.x;
    int base = t * 40;
    int local[40];
    int sum = 0;
#pragma unroll
    for (int k = 0; k < 40; k++) {
        int i = base + k;
        int c = (i < NN) ? counts[i] : 0;
        local[k] = sum;
        sum += c;
    }
    part[t] = sum;
    __syncthreads();
    for (int off = 1; off < 256; off <<= 1) {
        int v = (t >= off) ? part[t - off] : 0;
        __syncthreads();
        part[t] += v;
        __syncthreads();
    }
    int excl = part[t] - sum;
#pragma unroll
    for (int k = 0; k < 40; k++) {
        int i = base + k;
        if (i < NN) indptr[i] = excl + local[k];
    }
    if (t == 255) indptr[NN] = part[255];
}

__global__ void fill_kernel(const void* ei, const int* flag, const int* indptr,
                            int* cursor, int* csr_src) {
    int e = blockIdx.x * blockDim.x + threadIdx.x;
    if (e >= NET) return;
    int s, d;
    if (e < NE) load_edge(ei, *flag, e, s, d);
    else { s = e - NE; d = s; }
    int pos = indptr[d] + atomicAdd(&cursor[d], 1);
    csr_src[pos] = s;
}

// ---- f32 -> bf16 convert, 4 elems/thread
__global__ void cvt_kernel(const float* __restrict__ in, unsigned short* __restrict__ out, int n4) {
    int i = blockIdx.x * blockDim.x + threadIdx.x;
    if (i >= n4) return;
    float4 v = reinterpret_cast<const float4*>(in)[i];
    ushort4 o;
    o.x = f2b(v.x); o.y = f2b(v.y); o.z = f2b(v.z); o.w = f2b(v.w);
    reinterpret_cast<ushort4*>(out)[i] = o;
}

// ---- W [R][C] f32 -> Wt [C][R] bf16 (tiled transpose)
__global__ __launch_bounds__(256) void tpose_kernel(const float* __restrict__ in,
                                                    unsigned short* __restrict__ out,
                                                    int R, int C) {
    __shared__ float tile[32][33];
    int tx = threadIdx.x & 31, ty = threadIdx.x >> 5;
    int c = blockIdx.x * 32 + tx;
#pragma unroll
    for (int r0 = 0; r0 < 32; r0 += 8) {
        int r = blockIdx.y * 32 + ty + r0;
        tile[ty + r0][tx] = (r < R && c < C) ? in[(size_t)r * C + c] : 0.f;
    }
    __syncthreads();
    int oc = blockIdx.y * 32 + tx;   // R-dim
#pragma unroll
    for (int r0 = 0; r0 < 32; r0 += 8) {
        int orow = blockIdx.x * 32 + ty + r0;  // C-dim
        if (orow < C && oc < R)
            out[(size_t)orow * R + oc] = f2b(tile[tx][ty + r0]);
    }
}

// ---- C[M][N] = A[M][K](bf16) @ B[N][K](bf16)^T ; m97 structure:
// 128x128 tile, BK=32, 4 waves (2x2 of 64x64), global_load_lds width 16.
#define BM 128
#define BN 128
#define BK 32
__global__ __launch_bounds__(256) void gemm128(
    const unsigned short* __restrict__ A, const unsigned short* __restrict__ B,
    const float* __restrict__ bias, float* __restrict__ Cf, unsigned short* __restrict__ Cb,
    int M, int N, int K) {
    __shared__ __align__(16) unsigned short As[BM * BK];  // 8 KB, linear row-major [128][32]
    __shared__ __align__(16) unsigned short Bs[BN * BK];  // 8 KB
    int t = threadIdx.x;
    int row0 = blockIdx.x * BM, col0 = blockIdx.y * BN;
    int w = t >> 6, l = t & 63;
    int wr = w >> 1, wc = w & 1;
    f32x4 acc[4][4] = {};

    // staging: thread t covers 16B at linear offset t*8 shorts of each half-tile
    int sr = t >> 2;              // 0..63 (row within half-tile)
    int sc = (t & 3) * 8;         // k offset in shorts
    int arow0 = min(row0 + sr, M - 1);        // clamp: dup rows only feed unwritten C rows
    int arow1 = min(row0 + 64 + sr, M - 1);
    const unsigned short* aptr0 = A + (size_t)arow0 * K + sc;
    const unsigned short* aptr1 = A + (size_t)arow1 * K + sc;
    const unsigned short* bptr0 = B + (size_t)(col0 + sr) * K + sc;
    const unsigned short* bptr1 = B + (size_t)(col0 + 64 + sr) * K + sc;
    unsigned short* asd0 = As + w * 512;          // wave-uniform LDS dests
    unsigned short* asd1 = As + 2048 + w * 512;
    unsigned short* bsd0 = Bs + w * 512;
    unsigned short* bsd1 = Bs + 2048 + w * 512;

    int rr = l & 15;
    int kk = (l >> 4) * 8;

    for (int k0 = 0; k0 < K; k0 += BK) {
        __builtin_amdgcn_global_load_lds(
            (const __attribute__((address_space(1))) void*)(aptr0 + k0),
            (__attribute__((address_space(3))) void*)asd0, 16, 0, 0);
        __builtin_amdgcn_global_load_lds(
            (const __attribute__((address_space(1))) void*)(aptr1 + k0),
            (__attribute__((address_space(3))) void*)asd1, 16, 0, 0);
        __builtin_amdgcn_global_load_lds(
            (const __attribute__((address_space(1))) void*)(bptr0 + k0),
            (__attribute__((address_space(3))) void*)bsd0, 16, 0, 0);
        __builtin_amdgcn_global_load_lds(
            (const __attribute__((address_space(1))) void*)(bptr1 + k0),
            (__attribute__((address_space(3))) void*)bsd1, 16, 0, 0);
        __syncthreads();

        bf16x8 af[4], bfv[4];
#pragma unroll
        for (int mi = 0; mi < 4; mi++)
            af[mi] = *reinterpret_cast<const bf16x8*>(&As[(wr * 64 + mi * 16 + rr) * BK + kk]);
#pragma unroll
        for (int ni = 0; ni < 4; ni++)
            bfv[ni] = *reinterpret_cast<const bf16x8*>(&Bs[(wc * 64 + ni * 16 + rr) * BK + kk]);
#pragma unroll
        for (int mi = 0; mi < 4; mi++)
#pragma unroll
            for (int ni = 0; ni < 4; ni++)
                acc[mi][ni] = __builtin_amdgcn_mfma_f32_16x16x32_bf16(af[mi], bfv[ni], acc[mi][ni], 0, 0, 0);
        __syncthreads();
    }

    // C/D: col = lane&15, row = (lane>>4)*4 + j
    int c_l = l & 15, r_h = (l >> 4) * 4;
#pragma unroll
    for (int mi = 0; mi < 4; mi++)
#pragma unroll
        for (int ni = 0; ni < 4; ni++) {
            int gc = col0 + wc * 64 + ni * 16 + c_l;
#pragma unroll
            for (int j = 0; j < 4; j++) {
                int gr = row0 + wr * 64 + mi * 16 + r_h + j;
                if (gr < M) {
                    float v = acc[mi][ni][j];
                    if (bias) v += bias[gc];
                    if (Cf) Cf[(size_t)gr * N + gc] = v;
                    if (Cb) Cb[(size_t)gr * N + gc] = f2b(v);
                }
            }
        }
}

// ---- a_src/a_dst: per node, per head dot(h[n,h,:], att[h,:]); wave == head
__global__ __launch_bounds__(256) void att_kernel(const unsigned short* __restrict__ hb,
                                                  const float* __restrict__ att_s,
                                                  const float* __restrict__ att_d,
                                                  float* __restrict__ aS, float* __restrict__ aD) {
    int n = blockIdx.x;
    int t = threadIdx.x;
    int head = t >> 6, lane = t & 63;
    const unsigned short* hrow = hb + (size_t)n * D1 + head * HID + lane * 4;
    ushort4 hv = *reinterpret_cast<const ushort4*>(hrow);
    float4 as = *reinterpret_cast<const float4*>(att_s + head * HID + lane * 4);
    float4 ad = *reinterpret_cast<const float4*>(att_d + head * HID + lane * 4);
    float h0 = b2f(hv.x), h1 = b2f(hv.y), h2 = b2f(hv.z), h3 = b2f(hv.w);
    float ps = h0 * as.x + h1 * as.y + h2 * as.z + h3 * as.w;
    float pd = h0 * ad.x + h1 * ad.y + h2 * ad.z + h3 * ad.w;
#pragma unroll
    for (int off = 32; off; off >>= 1) {
        ps += __shfl_xor(ps, off);
        pd += __shfl_xor(pd, off);
    }
    if (lane == 0) {
        aS[n * HEADS + head] = ps;
        aD[n * HEADS + head] = pd;
    }
}

// ---- per-dst-node softmax + aggregation, fused bias+ReLU, bf16 out
__global__ __launch_bounds__(256) void agg_kernel(const unsigned short* __restrict__ hb,
                                                  const float* __restrict__ aS,
                                                  const float* __restrict__ aD,
                                                  const int* __restrict__ indptr,
                                                  const int* __restrict__ csr_src,
                                                  const float* __restrict__ bias,
                                                  unsigned short* __restrict__ outb) {
    int i = blockIdx.x;
    int t = threadIdx.x;
    int beg = indptr[i], end = indptr[i + 1];
    int deg = end - beg;
    __shared__ float sm[HEADS], ss[HEADS];
    __shared__ float alpha_s[64 * HEADS];
    __shared__ int src_s[64];
    float4 adst = *reinterpret_cast<const float4*>(aD + i * HEADS);
    // phase 1 (wave 0): per-head max then sum of exp
    if (t < 64) {
        float mx[4] = {-1e30f, -1e30f, -1e30f, -1e30f};
        for (int j = t; j < deg; j += 64) {
            int s = csr_src[beg + j];
            float4 asrc = *reinterpret_cast<const float4*>(aS + s * HEADS);
            mx[0] = fmaxf(mx[0], lrelu(asrc.x + adst.x));
            mx[1] = fmaxf(mx[1], lrelu(asrc.y + adst.y));
            mx[2] = fmaxf(mx[2], lrelu(asrc.z + adst.z));
            mx[3] = fmaxf(mx[3], lrelu(asrc.w + adst.w));
        }
#pragma unroll
        for (int off = 32; off; off >>= 1) {
#pragma unroll
            for (int h = 0; h < 4; h++) mx[h] = fmaxf(mx[h], __shfl_xor(mx[h], off));
        }
        float sum[4] = {0.f, 0.f, 0.f, 0.f};
        for (int j = t; j < deg; j += 64) {
            int s = csr_src[beg + j];
            float4 asrc = *reinterpret_cast<const float4*>(aS + s * HEADS);
            sum[0] += __expf(lrelu(asrc.x + adst.x) - mx[0]);
            sum[1] += __expf(lrelu(asrc.y + adst.y) - mx[1]);
            sum[2] += __expf(lrelu(asrc.z + adst.z) - mx[2]);
            sum[3] += __expf(lrelu(asrc.w + adst.w) - mx[3]);
        }
#pragma unroll
        for (int off = 32; off; off >>= 1) {
#pragma unroll
            for (int h = 0; h < 4; h++) sum[h] += __shfl_xor(sum[h], off);
        }
        if (t == 0) {
#pragma unroll
            for (int h = 0; h < 4; h++) { sm[h] = mx[h]; ss[h] = sum[h] + 1e-16f; }
        }
    }
    __syncthreads();
    // phase 2: chunked aggregation; thread t owns channels 4t..4t+3 (head t>>6)
    int head = t >> 6;
    float acc0 = 0.f, acc1 = 0.f, acc2 = 0.f, acc3 = 0.f;
    for (int c0 = 0; c0 < deg; c0 += 64) {
        int nj = min(64, deg - c0);
        if (t < nj) {
            int s = csr_src[beg + c0 + t];
            src_s[t] = s;
            float4 asrc = *reinterpret_cast<const float4*>(aS + s * HEADS);
            alpha_s[t * 4 + 0] = __expf(lrelu(asrc.x + adst.x) - sm[0]) / ss[0];
            alpha_s[t * 4 + 1] = __expf(lrelu(asrc.y + adst.y) - sm[1]) / ss[1];
            alpha_s[t * 4 + 2] = __expf(lrelu(asrc.z + adst.z) - sm[2]) / ss[2];
            alpha_s[t * 4 + 3] = __expf(lrelu(asrc.w + adst.w) - sm[3]) / ss[3];
        }
        __syncthreads();
        for (int j = 0; j < nj; j++) {
            int s = src_s[j];
            float wgt = alpha_s[j * 4 + head];
            ushort4 hv = *reinterpret_cast<const ushort4*>(hb + (size_t)s * D1 + t * 4);
            acc0 += wgt * b2f(hv.x);
            acc1 += wgt * b2f(hv.y);
            acc2 += wgt * b2f(hv.z);
            acc3 += wgt * b2f(hv.w);
        }
        __syncthreads();
    }
    float4 bv = *reinterpret_cast<const float4*>(bias + t * 4);
    ushort4 o;
    o.x = f2b(fmaxf(acc0 + bv.x, 0.f));
    o.y = f2b(fmaxf(acc1 + bv.y, 0.f));
    o.z = f2b(fmaxf(acc2 + bv.z, 0.f));
    o.w = f2b(fmaxf(acc3 + bv.w, 0.f));
    *reinterpret_cast<ushort4*>(outb + (size_t)i * D1 + t * 4) = o;
}

extern "C" void kernel_launch(void* const* d_in, const int* in_sizes, int n_in,
                              void* d_out, int out_size, void* d_ws, size_t ws_size,
                              hipStream_t stream) {
    const float* x   = (const float*)d_in[0];
    const void*  ei  = d_in[1];
    const float* W1  = (const float*)d_in[2];
    const float* as1 = (const float*)d_in[3];
    const float* ad1 = (const float*)d_in[4];
    const float* b1  = (const float*)d_in[5];
    const float* W2  = (const float*)d_in[6];
    const float* as2 = (const float*)d_in[7];
    const float* ad2 = (const float*)d_in[8];
    const float* b2  = (const float*)d_in[9];
    const float* fcW = (const float*)d_in[10];
    const float* fcb = (const float*)d_in[11];
    float* out = (float*)d_out;

    char* ws = (char*)d_ws;
    size_t o = 0;
    auto carve = [&](size_t bytes) -> char* {
        char* p = ws + o;
        o = (o + bytes + 255) & ~(size_t)255;
        return p;
    };
    unsigned short* xb   = (unsigned short*)carve((size_t)NN * IN_DIM * 2);
    unsigned short* hb   = (unsigned short*)carve((size_t)NN * D1 * 2);
    unsigned short* x2b  = (unsigned short*)carve((size_t)NN * D1 * 2);
    unsigned short* W1t  = (unsigned short*)carve((size_t)D1 * IN_DIM * 2);
    unsigned short* W2t  = (unsigned short*)carve((size_t)D1 * D1 * 2);
    unsigned short* fcWt = (unsigned short*)carve((size_t)OUT_DIM * D1 * 2);
    float* aS   = (float*)carve((size_t)NN * HEADS * 4);
    float* aD   = (float*)carve((size_t)NN * HEADS * 4);
    int* counts = (int*)carve((size_t)NN * 4);
    int* cursor = (int*)carve((size_t)NN * 4);
    int* indptr = (int*)carve((size_t)(NN + 1) * 4);
    int* csr_src= (int*)carve((size_t)NET * 4);
    int* flag   = (int*)carve(4);
    (void)ws_size; (void)in_sizes; (void)n_in; (void)out_size;

    // CSR build (dtype-agnostic edge loads)
    detect_kernel<<<1, 256, 0, stream>>>((const int*)ei, flag);
    zero2_kernel<<<(NN + 255) / 256, 256, 0, stream>>>(counts, cursor, NN);
    count_kernel<<<(NET + 255) / 256, 256, 0, stream>>>(ei, flag, counts);
    scan_kernel<<<1, 256, 0, stream>>>(counts, indptr);
    fill_kernel<<<(NET + 255) / 256, 256, 0, stream>>>(ei, flag, indptr, cursor, csr_src);

    // bf16 conversions
    cvt_kernel<<<(NN * IN_DIM / 4 + 255) / 256, 256, 0, stream>>>(x, xb, NN * IN_DIM / 4);
    tpose_kernel<<<dim3(D1 / 32, IN_DIM / 32), 256, 0, stream>>>(W1, W1t, IN_DIM, D1);
    tpose_kernel<<<dim3(D1 / 32, D1 / 32), 256, 0, stream>>>(W2, W2t, D1, D1);
    tpose_kernel<<<dim3(OUT_DIM / 32, D1 / 32), 256, 0, stream>>>(fcW, fcWt, D1, OUT_DIM);

    const int MB = (NN + BM - 1) / BM;  // 79
    // layer 1
    gemm128<<<dim3(MB, D1 / BN), 256, 0, stream>>>(xb, W1t, nullptr, nullptr, hb, NN, D1, IN_DIM);
    att_kernel<<<NN, 256, 0, stream>>>(hb, as1, ad1, aS, aD);
    agg_kernel<<<NN, 256, 0, stream>>>(hb, aS, aD, indptr, csr_src, b1, x2b);
    // layer 2
    gemm128<<<dim3(MB, D1 / BN), 256, 0, stream>>>(x2b, W2t, nullptr, nullptr, hb, NN, D1, D1);
    att_kernel<<<NN, 256, 0, stream>>>(hb, as2, ad2, aS, aD);
    agg_kernel<<<NN, 256, 0, stream>>>(hb, aS, aD, indptr, csr_src, b2, x2b);
    // final fc (bias, f32 out)
    gemm128<<<dim3(MB, OUT_DIM / BN), 256, 0, stream>>>(x2b, fcWt, fcb, out, nullptr, NN, OUT_DIM, D1);
}

// Round 3
// 272.369 us; speedup vs baseline: 1.1663x; 1.0497x over previous
//
#include <hip/hip_runtime.h>
#include <hip/hip_bf16.h>

#define NN 10000
#define NE 160000
#define NET 170000   // edges + self loops
#define IN_DIM 512
#define D1 1024      // HEADS*HID
#define HEADS 4
#define HID 256
#define OUT_DIM 512
#define NEG_SLOPE 0.2f

typedef __attribute__((ext_vector_type(8))) short bf16x8;
typedef __attribute__((ext_vector_type(4))) float f32x4;

__device__ inline float b2f(unsigned short b) {
    union { unsigned u; float f; } x; x.u = ((unsigned)b) << 16; return x.f;
}
__device__ inline unsigned short f2b(float f) {
    union { float f; unsigned u; } x; x.f = f;
    unsigned u = x.u;
    unsigned r = u + 0x7FFFu + ((u >> 16) & 1u);
    return (unsigned short)(r >> 16);
}
__device__ inline float lrelu(float v) { return v > 0.f ? v : NEG_SLOPE * v; }

// ---- init: zero counts/cursor; block 0 also detects edge_index dtype
// (int64 -> high words of first 500 values are all 0)
__global__ void init_kernel(const int* ei32, int* flag, int* counts, int* cursor) {
    int i = blockIdx.x * blockDim.x + threadIdx.x;
    if (i < NN) { counts[i] = 0; cursor[i] = 0; }
    if (blockIdx.x == 0) {
        __shared__ int nz;
        if (threadIdx.x == 0) nz = 0;
        __syncthreads();
        int acc = 0;
        for (int k = threadIdx.x; k < 500; k += 256) acc |= ei32[2 * k + 1];
        if (acc) atomicOr(&nz, 1);
        __syncthreads();
        if (threadIdx.x == 0) flag[0] = (nz == 0) ? 1 : 0;
    }
}

__device__ inline void load_edge(const void* ei, int f64, int e, int& s, int& d) {
    if (f64) {
        const long long* p = (const long long*)ei;
        s = (int)p[e]; d = (int)p[NE + e];
    } else {
        const int* p = (const int*)ei;
        s = p[e]; d = p[NE + e];
    }
}

__global__ void count_kernel(const void* ei, const int* flag, int* counts) {
    int e = blockIdx.x * blockDim.x + threadIdx.x;
    if (e >= NET) return;
    int s, d;
    if (e < NE) load_edge(ei, *flag, e, s, d);
    else d = e - NE;
    atomicAdd(&counts[d], 1);
}

__global__ __launch_bounds__(256) void scan_kernel(const int* counts, int* indptr) {
    __shared__ int part[256];
    int t = threadIdx.x;
    int base = t * 40;
    int local[40];
    int sum = 0;
#pragma unroll
    for (int k = 0; k < 40; k++) {
        int i = base + k;
        int c = (i < NN) ? counts[i] : 0;
        local[k] = sum;
        sum += c;
    }
    part[t] = sum;
    __syncthreads();
    for (int off = 1; off < 256; off <<= 1) {
        int v = (t >= off) ? part[t - off] : 0;
        __syncthreads();
        part[t] += v;
        __syncthreads();
    }
    int excl = part[t] - sum;
#pragma unroll
    for (int k = 0; k < 40; k++) {
        int i = base + k;
        if (i < NN) indptr[i] = excl + local[k];
    }
    if (t == 255) indptr[NN] = part[255];
}

__global__ void fill_kernel(const void* ei, const int* flag, const int* indptr,
                            int* cursor, int* csr_src) {
    int e = blockIdx.x * blockDim.x + threadIdx.x;
    if (e >= NET) return;
    int s, d;
    if (e < NE) load_edge(ei, *flag, e, s, d);
    else { s = e - NE; d = s; }
    int pos = indptr[d] + atomicAdd(&cursor[d], 1);
    csr_src[pos] = s;
}

// ---- prep: fused x->bf16 convert + 3 weight transposes (sectioned 1D grid)
__device__ void tpose_tile(const float* __restrict__ in, unsigned short* __restrict__ out,
                           int R, int C, int bx, int by) {
    __shared__ float tile[32][33];
    int tx = threadIdx.x & 31, ty = threadIdx.x >> 5;
    int c = bx * 32 + tx;
#pragma unroll
    for (int r0 = 0; r0 < 32; r0 += 8) {
        int r = by * 32 + ty + r0;
        tile[ty + r0][tx] = in[(size_t)r * C + c];
    }
    __syncthreads();
    int oc = by * 32 + tx;
#pragma unroll
    for (int r0 = 0; r0 < 32; r0 += 8) {
        int orow = bx * 32 + ty + r0;
        out[(size_t)orow * R + oc] = f2b(tile[tx][ty + r0]);
    }
}

#define CVT_NB 5000   // NN*IN_DIM/4/256
#define TP1_NB 512    // (D1/32)*(IN_DIM/32)
#define TP2_NB 1024   // (D1/32)*(D1/32)
#define TP3_NB 512    // (OUT_DIM/32)*(D1/32)
__global__ __launch_bounds__(256) void prep_kernel(
    const float* __restrict__ x, unsigned short* __restrict__ xb,
    const float* __restrict__ W1, unsigned short* __restrict__ W1t,
    const float* __restrict__ W2, unsigned short* __restrict__ W2t,
    const float* __restrict__ fcW, unsigned short* __restrict__ fcWt) {
    int b = blockIdx.x;
    if (b < CVT_NB) {
        int i = b * 256 + threadIdx.x;
        float4 v = reinterpret_cast<const float4*>(x)[i];
        ushort4 o;
        o.x = f2b(v.x); o.y = f2b(v.y); o.z = f2b(v.z); o.w = f2b(v.w);
        reinterpret_cast<ushort4*>(xb)[i] = o;
        return;
    }
    b -= CVT_NB;
    if (b < TP1_NB) { tpose_tile(W1, W1t, IN_DIM, D1, b & 31, b >> 5); return; }
    b -= TP1_NB;
    if (b < TP2_NB) { tpose_tile(W2, W2t, D1, D1, b & 31, b >> 5); return; }
    b -= TP2_NB;
    tpose_tile(fcW, fcWt, D1, OUT_DIM, b & 15, b >> 4);
}

// ---- C[M][N] = A[M][K](bf16) @ B[N][K](bf16)^T ; m97 structure:
// 128x128 tile, BK=32, 4 waves (2x2 of 64x64), global_load_lds width 16.
#define BM 128
#define BN 128
#define BK 32
__global__ __launch_bounds__(256) void gemm128(
    const unsigned short* __restrict__ A, const unsigned short* __restrict__ B,
    const float* __restrict__ bias, float* __restrict__ Cf, unsigned short* __restrict__ Cb,
    int M, int N, int K) {
    __shared__ __align__(16) unsigned short As[BM * BK];  // 8 KB, linear row-major [128][32]
    __shared__ __align__(16) unsigned short Bs[BN * BK];  // 8 KB
    int t = threadIdx.x;
    int row0 = blockIdx.x * BM, col0 = blockIdx.y * BN;
    int w = t >> 6, l = t & 63;
    int wr = w >> 1, wc = w & 1;
    f32x4 acc[4][4] = {};

    int sr = t >> 2;              // 0..63 (row within half-tile)
    int sc = (t & 3) * 8;         // k offset in shorts
    int arow0 = min(row0 + sr, M - 1);        // clamp: dup rows only feed unwritten C rows
    int arow1 = min(row0 + 64 + sr, M - 1);
    const unsigned short* aptr0 = A + (size_t)arow0 * K + sc;
    const unsigned short* aptr1 = A + (size_t)arow1 * K + sc;
    const unsigned short* bptr0 = B + (size_t)(col0 + sr) * K + sc;
    const unsigned short* bptr1 = B + (size_t)(col0 + 64 + sr) * K + sc;
    unsigned short* asd0 = As + w * 512;          // wave-uniform LDS dests
    unsigned short* asd1 = As + 2048 + w * 512;
    unsigned short* bsd0 = Bs + w * 512;
    unsigned short* bsd1 = Bs + 2048 + w * 512;

    int rr = l & 15;
    int kk = (l >> 4) * 8;

    for (int k0 = 0; k0 < K; k0 += BK) {
        __builtin_amdgcn_global_load_lds(
            (const __attribute__((address_space(1))) void*)(aptr0 + k0),
            (__attribute__((address_space(3))) void*)asd0, 16, 0, 0);
        __builtin_amdgcn_global_load_lds(
            (const __attribute__((address_space(1))) void*)(aptr1 + k0),
            (__attribute__((address_space(3))) void*)asd1, 16, 0, 0);
        __builtin_amdgcn_global_load_lds(
            (const __attribute__((address_space(1))) void*)(bptr0 + k0),
            (__attribute__((address_space(3))) void*)bsd0, 16, 0, 0);
        __builtin_amdgcn_global_load_lds(
            (const __attribute__((address_space(1))) void*)(bptr1 + k0),
            (__attribute__((address_space(3))) void*)bsd1, 16, 0, 0);
        __syncthreads();

        bf16x8 af[4], bfv[4];
#pragma unroll
        for (int mi = 0; mi < 4; mi++)
            af[mi] = *reinterpret_cast<const bf16x8*>(&As[(wr * 64 + mi * 16 + rr) * BK + kk]);
#pragma unroll
        for (int ni = 0; ni < 4; ni++)
            bfv[ni] = *reinterpret_cast<const bf16x8*>(&Bs[(wc * 64 + ni * 16 + rr) * BK + kk]);
#pragma unroll
        for (int mi = 0; mi < 4; mi++)
#pragma unroll
            for (int ni = 0; ni < 4; ni++)
                acc[mi][ni] = __builtin_amdgcn_mfma_f32_16x16x32_bf16(af[mi], bfv[ni], acc[mi][ni], 0, 0, 0);
        __syncthreads();
    }

    // C/D: col = lane&15, row = (lane>>4)*4 + j
    int c_l = l & 15, r_h = (l >> 4) * 4;
#pragma unroll
    for (int mi = 0; mi < 4; mi++)
#pragma unroll
        for (int ni = 0; ni < 4; ni++) {
            int gc = col0 + wc * 64 + ni * 16 + c_l;
#pragma unroll
            for (int j = 0; j < 4; j++) {
                int gr = row0 + wr * 64 + mi * 16 + r_h + j;
                if (gr < M) {
                    float v = acc[mi][ni][j];
                    if (bias) v += bias[gc];
                    if (Cf) Cf[(size_t)gr * N + gc] = v;
                    if (Cb) Cb[(size_t)gr * N + gc] = f2b(v);
                }
            }
        }
}

// ---- a_src/a_dst: per node, per head dot(h[n,h,:], att[h,:]); wave == head
__global__ __launch_bounds__(256) void att_kernel(const unsigned short* __restrict__ hb,
                                                  const float* __restrict__ att_s,
                                                  const float* __restrict__ att_d,
                                                  float* __restrict__ aS, float* __restrict__ aD) {
    int n = blockIdx.x;
    int t = threadIdx.x;
    int head = t >> 6, lane = t & 63;
    const unsigned short* hrow = hb + (size_t)n * D1 + head * HID + lane * 4;
    ushort4 hv = *reinterpret_cast<const ushort4*>(hrow);
    float4 as = *reinterpret_cast<const float4*>(att_s + head * HID + lane * 4);
    float4 ad = *reinterpret_cast<const float4*>(att_d + head * HID + lane * 4);
    float h0 = b2f(hv.x), h1 = b2f(hv.y), h2 = b2f(hv.z), h3 = b2f(hv.w);
    float ps = h0 * as.x + h1 * as.y + h2 * as.z + h3 * as.w;
    float pd = h0 * ad.x + h1 * ad.y + h2 * ad.z + h3 * ad.w;
#pragma unroll
    for (int off = 32; off; off >>= 1) {
        ps += __shfl_xor(ps, off);
        pd += __shfl_xor(pd, off);
    }
    if (lane == 0) {
        aS[n * HEADS + head] = ps;
        aD[n * HEADS + head] = pd;
    }
}

// ---- per-dst-node softmax + aggregation, fused bias+ReLU, bf16 out
// deferred normalization: acc = sum(e*h), divide by sum(e) at the end.
// inner loop unrolled x4 with register prefetch (4 rows / 8KB in flight).
__global__ __launch_bounds__(256) void agg_kernel(const unsigned short* __restrict__ hb,
                                                  const float* __restrict__ aS,
                                                  const float* __restrict__ aD,
                                                  const int* __restrict__ indptr,
                                                  const int* __restrict__ csr_src,
                                                  const float* __restrict__ bias,
                                                  unsigned short* __restrict__ outb) {
    int i = blockIdx.x;
    int t = threadIdx.x;
    int beg = indptr[i], end = indptr[i + 1];
    int deg = end - beg;
    __shared__ float sm[HEADS], ss[HEADS];
    __shared__ float alpha_s[64 * HEADS];
    __shared__ int src_s[64];
    float4 adst = *reinterpret_cast<const float4*>(aD + i * HEADS);
    // phase 1 (wave 0): per-head max only
    if (t < 64) {
        float mx0 = -1e30f, mx1 = -1e30f, mx2 = -1e30f, mx3 = -1e30f;
        for (int j = t; j < deg; j += 64) {
            int s = csr_src[beg + j];
            float4 a = *reinterpret_cast<const float4*>(aS + s * HEADS);
            mx0 = fmaxf(mx0, lrelu(a.x + adst.x));
            mx1 = fmaxf(mx1, lrelu(a.y + adst.y));
            mx2 = fmaxf(mx2, lrelu(a.z + adst.z));
            mx3 = fmaxf(mx3, lrelu(a.w + adst.w));
        }
#pragma unroll
        for (int off = 32; off; off >>= 1) {
            mx0 = fmaxf(mx0, __shfl_xor(mx0, off));
            mx1 = fmaxf(mx1, __shfl_xor(mx1, off));
            mx2 = fmaxf(mx2, __shfl_xor(mx2, off));
            mx3 = fmaxf(mx3, __shfl_xor(mx3, off));
        }
        if (t == 0) { sm[0] = mx0; sm[1] = mx1; sm[2] = mx2; sm[3] = mx3; }
    }
    if (t >= 64 && t < 68) ss[t - 64] = 0.f;
    __syncthreads();
    int head = t >> 6, lane = t & 63;
    float acc0 = 0.f, acc1 = 0.f, acc2 = 0.f, acc3 = 0.f;
    for (int c0 = 0; c0 < deg; c0 += 64) {
        int nj = min(64, deg - c0);
        if (t < 64) {
            int s = 0;
            float e0 = 0.f, e1 = 0.f, e2 = 0.f, e3 = 0.f;
            if (t < nj) {
                s = csr_src[beg + c0 + t];
                float4 a = *reinterpret_cast<const float4*>(aS + s * HEADS);
                e0 = __expf(lrelu(a.x + adst.x) - sm[0]);
                e1 = __expf(lrelu(a.y + adst.y) - sm[1]);
                e2 = __expf(lrelu(a.z + adst.z) - sm[2]);
                e3 = __expf(lrelu(a.w + adst.w) - sm[3]);
            }
            src_s[t] = s;
            alpha_s[t * 4 + 0] = e0;
            alpha_s[t * 4 + 1] = e1;
            alpha_s[t * 4 + 2] = e2;
            alpha_s[t * 4 + 3] = e3;
        }
        __syncthreads();
        // per-head chunk sum of e (wave w == head w)
        {
            float v = alpha_s[lane * 4 + head];
#pragma unroll
            for (int off = 32; off; off >>= 1) v += __shfl_xor(v, off);
            if (lane == 0) ss[head] += v;
        }
        // unrolled-x4 accumulate with register prefetch
        int njr = (nj + 3) & ~3;
        const unsigned short* hp = hb + (size_t)t * 4;
        ushort4 p0 = *reinterpret_cast<const ushort4*>(hp + (size_t)src_s[0] * D1);
        ushort4 p1 = *reinterpret_cast<const ushort4*>(hp + (size_t)src_s[1] * D1);
        ushort4 p2 = *reinterpret_cast<const ushort4*>(hp + (size_t)src_s[2] * D1);
        ushort4 p3 = *reinterpret_cast<const ushort4*>(hp + (size_t)src_s[3] * D1);
        for (int j = 0; j < njr; j += 4) {
            float w0 = alpha_s[(j + 0) * 4 + head];
            float w1 = alpha_s[(j + 1) * 4 + head];
            float w2 = alpha_s[(j + 2) * 4 + head];
            float w3 = alpha_s[(j + 3) * 4 + head];
            ushort4 c0v = p0, c1v = p1, c2v = p2, c3v = p3;
            if (j + 4 < njr) {  // uniform branch; src_s[j+4..j+7] always initialized
                p0 = *reinterpret_cast<const ushort4*>(hp + (size_t)src_s[j + 4] * D1);
                p1 = *reinterpret_cast<const ushort4*>(hp + (size_t)src_s[j + 5] * D1);
                p2 = *reinterpret_cast<const ushort4*>(hp + (size_t)src_s[j + 6] * D1);
                p3 = *reinterpret_cast<const ushort4*>(hp + (size_t)src_s[j + 7] * D1);
            }
            acc0 += w0 * b2f(c0v.x) + w1 * b2f(c1v.x) + w2 * b2f(c2v.x) + w3 * b2f(c3v.x);
            acc1 += w0 * b2f(c0v.y) + w1 * b2f(c1v.y) + w2 * b2f(c2v.y) + w3 * b2f(c3v.y);
            acc2 += w0 * b2f(c0v.z) + w1 * b2f(c1v.z) + w2 * b2f(c2v.z) + w3 * b2f(c3v.z);
            acc3 += w0 * b2f(c0v.w) + w1 * b2f(c1v.w) + w2 * b2f(c2v.w) + w3 * b2f(c3v.w);
        }
        __syncthreads();
    }
    float inv = 1.f / (ss[head] + 1e-16f);
    float4 bv = *reinterpret_cast<const float4*>(bias + t * 4);
    ushort4 o;
    o.x = f2b(fmaxf(acc0 * inv + bv.x, 0.f));
    o.y = f2b(fmaxf(acc1 * inv + bv.y, 0.f));
    o.z = f2b(fmaxf(acc2 * inv + bv.z, 0.f));
    o.w = f2b(fmaxf(acc3 * inv + bv.w, 0.f));
    *reinterpret_cast<ushort4*>(outb + (size_t)i * D1 + t * 4) = o;
}

extern "C" void kernel_launch(void* const* d_in, const int* in_sizes, int n_in,
                              void* d_out, int out_size, void* d_ws, size_t ws_size,
                              hipStream_t stream) {
    const float* x   = (const float*)d_in[0];
    const void*  ei  = d_in[1];
    const float* W1  = (const float*)d_in[2];
    const float* as1 = (const float*)d_in[3];
    const float* ad1 = (const float*)d_in[4];
    const float* b1  = (const float*)d_in[5];
    const float* W2  = (const float*)d_in[6];
    const float* as2 = (const float*)d_in[7];
    const float* ad2 = (const float*)d_in[8];
    const float* b2  = (const float*)d_in[9];
    const float* fcW = (const float*)d_in[10];
    const float* fcb = (const float*)d_in[11];
    float* out = (float*)d_out;

    char* ws = (char*)d_ws;
    size_t o = 0;
    auto carve = [&](size_t bytes) -> char* {
        char* p = ws + o;
        o = (o + bytes + 255) & ~(size_t)255;
        return p;
    };
    unsigned short* xb   = (unsigned short*)carve((size_t)NN * IN_DIM * 2);
    unsigned short* hb   = (unsigned short*)carve((size_t)NN * D1 * 2);
    unsigned short* x2b  = (unsigned short*)carve((size_t)NN * D1 * 2);
    unsigned short* W1t  = (unsigned short*)carve((size_t)D1 * IN_DIM * 2);
    unsigned short* W2t  = (unsigned short*)carve((size_t)D1 * D1 * 2);
    unsigned short* fcWt = (unsigned short*)carve((size_t)OUT_DIM * D1 * 2);
    float* aS   = (float*)carve((size_t)NN * HEADS * 4);
    float* aD   = (float*)carve((size_t)NN * HEADS * 4);
    int* counts = (int*)carve((size_t)NN * 4);
    int* cursor = (int*)carve((size_t)NN * 4);
    int* indptr = (int*)carve((size_t)(NN + 1) * 4);
    int* csr_src= (int*)carve((size_t)NET * 4);
    int* flag   = (int*)carve(4);
    (void)ws_size; (void)in_sizes; (void)n_in; (void)out_size;

    // CSR build (dtype-agnostic edge loads)
    init_kernel<<<(NN + 255) / 256, 256, 0, stream>>>((const int*)ei, flag, counts, cursor);
    count_kernel<<<(NET + 255) / 256, 256, 0, stream>>>(ei, flag, counts);
    scan_kernel<<<1, 256, 0, stream>>>(counts, indptr);
    fill_kernel<<<(NET + 255) / 256, 256, 0, stream>>>(ei, flag, indptr, cursor, csr_src);

    // fused conversions (cvt + 3 transposes)
    prep_kernel<<<CVT_NB + TP1_NB + TP2_NB + TP3_NB, 256, 0, stream>>>(
        x, xb, W1, W1t, W2, W2t, fcW, fcWt);

    const int MB = (NN + BM - 1) / BM;  // 79
    // layer 1
    gemm128<<<dim3(MB, D1 / BN), 256, 0, stream>>>(xb, W1t, nullptr, nullptr, hb, NN, D1, IN_DIM);
    att_kernel<<<NN, 256, 0, stream>>>(hb, as1, ad1, aS, aD);
    agg_kernel<<<NN, 256, 0, stream>>>(hb, aS, aD, indptr, csr_src, b1, x2b);
    // layer 2
    gemm128<<<dim3(MB, D1 / BN), 256, 0, stream>>>(x2b, W2t, nullptr, nullptr, hb, NN, D1, D1);
    att_kernel<<<NN, 256, 0, stream>>>(hb, as2, ad2, aS, aD);
    agg_kernel<<<NN, 256, 0, stream>>>(hb, aS, aD, indptr, csr_src, b2, x2b);
    // final fc (bias, f32 out)
    gemm128<<<dim3(MB, OUT_DIM / BN), 256, 0, stream>>>(x2b, fcWt, fcb, out, nullptr, NN, OUT_DIM, D1);
}